// Round 12
// baseline (1610.521 us; speedup 1.0000x reference)
//
#include <hip/hip_runtime.h>

typedef __bf16 bf16_t;
typedef __bf16 bf16x8 __attribute__((ext_vector_type(8)));
typedef __bf16 bf16x4 __attribute__((ext_vector_type(4)));
typedef float f32x4 __attribute__((ext_vector_type(4)));

#define MFMA16(a, b, c) __builtin_amdgcn_mfma_f32_16x16x32_bf16(a, b, c, 0, 0, 0)

__device__ __forceinline__ f32x4 zero4() {
    f32x4 z = {0.f, 0.f, 0.f, 0.f};
    return z;
}

__device__ __forceinline__ float gelu_f(float v) {
    float u = 0.7978845608028654f * (v + 0.044715f * v * v * v);
    float e = __expf(2.0f * u);
    float th = 1.0f - 2.0f / (e + 1.0f);  // tanh(u), overflow-safe
    return 0.5f * v * (1.0f + th);
}

__device__ __forceinline__ void gload16(const bf16_t* g, bf16_t* l) {
    __builtin_amdgcn_global_load_lds((const __attribute__((address_space(1))) void*)g,
                                     (__attribute__((address_space(3))) void*)l, 16, 0, 0);
}

// ---------------- embedding: x = wte[ids] + wpe; also layers_output[0] ----------------
__global__ __launch_bounds__(256) void embed_kernel(const int* __restrict__ ids,
                                                    const float* __restrict__ wte,
                                                    const float* __restrict__ wpe,
                                                    float* __restrict__ x,
                                                    float* __restrict__ out0) {
    const int s = blockIdx.x;
    const int id = ids[s];
    const size_t base = (size_t)s * 768;
#pragma unroll
    for (int r = 0; r < 3; ++r) {
        int d = threadIdx.x + r * 256;
        float v = wte[(size_t)id * 768 + d] + wpe[base + d];
        x[base + d] = v;
        out0[base + d] = v;
    }
}

// ---------------- layernorm (final only): one row per block, f32 out ------------------
__global__ __launch_bounds__(256) void ln_kernel(const float* __restrict__ x,
                                                 const float* __restrict__ w,
                                                 const float* __restrict__ b,
                                                 float* __restrict__ outp) {
    const int row = blockIdx.x;
    const int t = threadIdx.x;
    const float* xr = x + (size_t)row * 768;
    float v0 = xr[t], v1 = xr[t + 256], v2 = xr[t + 512];
    float s = v0 + v1 + v2;
    float q = v0 * v0 + v1 * v1 + v2 * v2;
#pragma unroll
    for (int off = 32; off >= 1; off >>= 1) {
        s += __shfl_xor(s, off);
        q += __shfl_xor(q, off);
    }
    __shared__ float sh_s[4], sh_q[4];
    if ((t & 63) == 0) {
        sh_s[t >> 6] = s;
        sh_q[t >> 6] = q;
    }
    __syncthreads();
    s = sh_s[0] + sh_s[1] + sh_s[2] + sh_s[3];
    q = sh_q[0] + sh_q[1] + sh_q[2] + sh_q[3];
    const float mean = s * (1.0f / 768.0f);
    const float var = q * (1.0f / 768.0f) - mean * mean;
    const float rstd = rsqrtf(var + 1e-5f);
    float vv[3] = {v0, v1, v2};
#pragma unroll
    for (int r = 0; r < 3; ++r) {
        int d = t + r * 256;
        outp[(size_t)row * 768 + d] = (vv[r] - mean) * rstd * w[d] + b[d];
    }
}

// ------- weight transpose + f32->bf16: src[z][K][N] -> dst[z][N][K], all layers -------
__global__ __launch_bounds__(256) void transpose_cvt(const float* __restrict__ src0,
                                                     bf16_t* __restrict__ dst0, int K, int N) {
    const int l = blockIdx.z;
    const float* src = src0 + (size_t)l * K * N;
    bf16_t* dst = dst0 + (size_t)l * N * K;
    const int n0 = blockIdx.x * 32;
    const int k0 = blockIdx.y * 32;
    __shared__ float tile[32][36];
    const int t = threadIdx.x;
    const int r = t >> 3, c4 = (t & 7) * 4;
    const float4 v = *(const float4*)&src[(size_t)(k0 + r) * N + n0 + c4];
    tile[r][c4 + 0] = v.x;
    tile[r][c4 + 1] = v.y;
    tile[r][c4 + 2] = v.z;
    tile[r][c4 + 3] = v.w;
    __syncthreads();
    bf16x4 o;
    o[0] = (bf16_t)tile[c4 + 0][r];
    o[1] = (bf16_t)tile[c4 + 1][r];
    o[2] = (bf16_t)tile[c4 + 2][r];
    o[3] = (bf16_t)tile[c4 + 3][r];
    *(bf16x4*)&dst[(size_t)(n0 + r) * K + k0 + c4] = o;
}

// --------- GEMM: C[1024,N] = A[1024,LDK] x BT[N,LDK]^T over KLEN ----------------------
// 4 waves (2x2), BK=64, XOR-swizzled row-major LDS, 3-buffer counted-vmcnt pipeline.
// LNA: A is LayerNorm(x) computed on the fly (stats prologue + reg-staged transform);
//      B stays global_load_lds. vmcnt schedule: A-group=4 f32x4, B-group=2 gload16.
// SLICE: epilogue also writes f32 to outF2. VT: scatter V^T for attention.
template <int BM, int BN, bool GELU, bool RES, bool VT, bool LNA, bool SLICE>
__global__ __launch_bounds__(256) void gemm3(const bf16_t* __restrict__ A,
                                             const float* __restrict__ Af32,
                                             const bf16_t* __restrict__ BT,
                                             const float* __restrict__ bias,
                                             const float* __restrict__ res,
                                             const float* __restrict__ lnw,
                                             const float* __restrict__ lnb,
                                             float* __restrict__ outF,
                                             float* __restrict__ outF2,
                                             bf16_t* __restrict__ outB,
                                             bf16_t* __restrict__ vt, int N, int LDK,
                                             int KLEN) {
    constexpr int MW = BM / 32, NW = BN / 32;
    constexpr int TILE = (BM + BN) * 64;
    constexpr int LOADS = (BM + BN) / 32;
    __shared__ __align__(16) bf16_t lds[3 * TILE];
    __shared__ bf16_t wls[2 * 768];  // LN w,b (bf16) when LNA
    __shared__ float mls[128];       // per-row mean,rstd when LNA
    const int tid = threadIdx.x;
    const int lane = tid & 63, wv = tid >> 6, wm = wv >> 1, wn = wv & 1;
    const int lr = lane & 15, lg = lane >> 4;
    const int m0 = blockIdx.x * BM, n0 = blockIdx.y * BN;
    const bf16_t* Ap = A + (size_t)m0 * LDK + (size_t)blockIdx.z * KLEN;
    const bf16_t* Bp = BT + (size_t)n0 * LDK + (size_t)blockIdx.z * KLEN;

    f32x4 acc[MW][NW];
#pragma unroll
    for (int i = 0; i < MW; ++i)
#pragma unroll
        for (int j = 0; j < NW; ++j) acc[i][j] = zero4();

    const int KT = KLEN >> 6;

    auto stageB = [&](int buf, int kt) {
        bf16_t* Bd = lds + buf * TILE + BM * 64;
#pragma unroll
        for (int i = 0; i < BN / 32; ++i) {
            int v = i * 256 + tid;
            int row = v >> 3, cg = v & 7;
            gload16(Bp + (size_t)row * LDK + kt * 64 + ((cg ^ (row & 7)) << 3), Bd + v * 8);
        }
    };
    auto stageA = [&](int buf, int kt) {  // !LNA path
        bf16_t* Ad = lds + buf * TILE;
#pragma unroll
        for (int i = 0; i < BM / 32; ++i) {
            int v = i * 256 + tid;
            int row = v >> 3, cg = v & 7;
            gload16(Ap + (size_t)row * LDK + kt * 64 + ((cg ^ (row & 7)) << 3), Ad + v * 8);
        }
    };
    // LNA helpers: per-thread 2 slots x 8 f32 of x (pre-swizzled col group)
    auto a_issue = [&](int kt, float4* regs) {
#pragma unroll
        for (int s2 = 0; s2 < 2; ++s2) {
            int v = s2 * 256 + tid;
            int row = v >> 3, cg = v & 7;
            int c8 = cg ^ (row & 7);
            const float* src = Af32 + (size_t)(m0 + row) * 768 + kt * 64 + c8 * 8;
            regs[s2 * 2 + 0] = *(const float4*)src;
            regs[s2 * 2 + 1] = *(const float4*)(src + 4);
        }
    };
    auto a_transform = [&](int buf, int kt, const float4* regs) {
        bf16_t* Ad = lds + buf * TILE;
#pragma unroll
        for (int s2 = 0; s2 < 2; ++s2) {
            int v = s2 * 256 + tid;
            int row = v >> 3, cg = v & 7;
            int c8 = cg ^ (row & 7);
            const float mean = mls[row * 2], rstd = mls[row * 2 + 1];
            const int cb = kt * 64 + c8 * 8;
            bf16x8 wv8 = *(const bf16x8*)&wls[cb];
            bf16x8 bv8 = *(const bf16x8*)&wls[768 + cb];
            bf16x8 o;
#pragma unroll
            for (int jj = 0; jj < 8; ++jj) {
                float xv = ((const float*)&regs[s2 * 2])[jj];
                o[jj] = (bf16_t)((xv - mean) * rstd * (float)wv8[jj] + (float)bv8[jj]);
            }
            *(bf16x8*)&Ad[v * 8] = o;
        }
    };

    auto compute = [&](int buf) {
        const bf16_t* Ab = lds + buf * TILE;
        const bf16_t* Bb = Ab + BM * 64;
        __builtin_amdgcn_s_setprio(1);
#pragma unroll
        for (int c = 0; c < 2; ++c) {
            bf16x8 af[MW], bfr[NW];
#pragma unroll
            for (int i = 0; i < MW; ++i) {
                int row = wm * (BM / 2) + i * 16 + lr;
                af[i] = *(const bf16x8*)&Ab[row * 64 + ((c * 32 + lg * 8) ^ ((row & 7) << 3))];
            }
#pragma unroll
            for (int j = 0; j < NW; ++j) {
                int row = wn * (BN / 2) + j * 16 + lr;
                bfr[j] = *(const bf16x8*)&Bb[row * 64 + ((c * 32 + lg * 8) ^ ((row & 7) << 3))];
            }
#pragma unroll
            for (int i = 0; i < MW; ++i)
#pragma unroll
                for (int j = 0; j < NW; ++j) acc[i][j] = MFMA16(af[i], bfr[j], acc[i][j]);
        }
        __builtin_amdgcn_s_setprio(0);
    };

    if constexpr (LNA) {
        // per-row LN stats: 4 threads/row over 192 cols each
        {
            const int srow = tid >> 2, sseg = tid & 3;
            const float* xr = Af32 + (size_t)(m0 + srow) * 768 + sseg * 192;
            float s = 0.f, q = 0.f;
#pragma unroll 8
            for (int j = 0; j < 48; ++j) {
                float4 v4 = *(const float4*)(xr + j * 4);
                s += v4.x + v4.y + v4.z + v4.w;
                q += v4.x * v4.x + v4.y * v4.y + v4.z * v4.z + v4.w * v4.w;
            }
            s += __shfl_xor(s, 1);
            s += __shfl_xor(s, 2);
            q += __shfl_xor(q, 1);
            q += __shfl_xor(q, 2);
            if (sseg == 0) {
                const float mean = s * (1.0f / 768.0f);
                const float var = q * (1.0f / 768.0f) - mean * mean;
                mls[srow * 2] = mean;
                mls[srow * 2 + 1] = rsqrtf(var + 1e-5f);
            }
            // LN w,b -> LDS bf16
            if (tid < 192) {
                float4 wv = *(const float4*)&lnw[tid * 4];
                float4 bv = *(const float4*)&lnb[tid * 4];
                bf16x4 wo, bo;
                wo[0] = (bf16_t)wv.x; wo[1] = (bf16_t)wv.y; wo[2] = (bf16_t)wv.z; wo[3] = (bf16_t)wv.w;
                bo[0] = (bf16_t)bv.x; bo[1] = (bf16_t)bv.y; bo[2] = (bf16_t)bv.z; bo[3] = (bf16_t)bv.w;
                *(bf16x4*)&wls[tid * 4] = wo;
                *(bf16x4*)&wls[768 + tid * 4] = bo;
            }
        }
        __syncthreads();

        float4 ar0[4], ar1[4];
        a_issue(0, ar0);       // 4 vmem
        stageB(0, 0);          // 2 vmem
        a_issue(1, ar1);       // 4 vmem
        stageB(1, 1);          // 2 vmem  (total 12 outstanding)
        asm volatile("s_waitcnt vmcnt(8)" ::: "memory");  // A0 arrived
        a_transform(0, 0, ar0);
        asm volatile("s_waitcnt vmcnt(2)" ::: "memory");  // A1 arrived (B1 in flight)
        a_transform(1, 1, ar1);

        int buf = 0;
        float4 ar[4];
        for (int kt = 0; kt < KT; ++kt) {
            if (kt + 1 < KT)
                asm volatile("s_waitcnt vmcnt(2) lgkmcnt(0)" ::: "memory");
            else
                asm volatile("s_waitcnt vmcnt(0) lgkmcnt(0)" ::: "memory");
            __builtin_amdgcn_s_barrier();
            if (kt + 2 < KT) {
                a_issue(kt + 2, ar);            // 4 vmem
                stageB((kt + 2) % 3, kt + 2);   // 2 vmem
            }
            compute(buf);
            if (kt + 2 < KT) {
                asm volatile("s_waitcnt vmcnt(2)" ::: "memory");  // A(kt+2) arrived
                a_transform((kt + 2) % 3, kt + 2, ar);
            }
            buf = (buf + 1) % 3;
        }
    } else {
        stageA(0, 0);
        stageB(0, 0);
        stageA(1, 1);
        stageB(1, 1);
        int buf = 0;
        for (int kt = 0; kt < KT; ++kt) {
            if (kt + 1 < KT) {
                if constexpr (LOADS == 4)
                    asm volatile("s_waitcnt vmcnt(4)" ::: "memory");
                else
                    asm volatile("s_waitcnt vmcnt(3)" ::: "memory");
            } else {
                asm volatile("s_waitcnt vmcnt(0)" ::: "memory");
            }
            __builtin_amdgcn_s_barrier();
            if (kt + 2 < KT) {
                stageA((kt + 2) % 3, kt + 2);
                stageB((kt + 2) % 3, kt + 2);
            }
            compute(buf);
            buf = (buf + 1) % 3;
        }
    }

    float* o1 = outF ? outF + (size_t)blockIdx.z * ((size_t)1024 * N) : nullptr;
    // epilogue: C/D layout col = lane&15, row = (lane>>4)*4 + reg
#pragma unroll
    for (int i = 0; i < MW; ++i) {
#pragma unroll
        for (int j = 0; j < NW; ++j) {
            const int col = n0 + wn * (BN / 2) + j * 16 + lr;
            const float bc = bias ? bias[col] : 0.f;
            float vr[4];
#pragma unroll
            for (int ii = 0; ii < 4; ++ii) {
                const int rrow = m0 + wm * (BM / 2) + i * 16 + lg * 4 + ii;
                float v = acc[i][j][ii] + bc;
                if (GELU) v = gelu_f(v);
                if (RES) v += res[(size_t)rrow * N + col];
                if (o1) o1[(size_t)rrow * N + col] = v;
                if (SLICE) outF2[(size_t)rrow * N + col] = v;
                if (outB) outB[(size_t)rrow * N + col] = (bf16_t)v;
                vr[ii] = v;
            }
            if (VT && col >= 1536) {  // transposed V: vt[d'][seq], 4 consecutive rows
                const int rrow0 = m0 + wm * (BM / 2) + i * 16 + lg * 4;
                bf16x4 o;
#pragma unroll
                for (int ii = 0; ii < 4; ++ii) o[ii] = (bf16_t)vr[ii];
                *(bf16x4*)&vt[(size_t)(col - 1536) * 1024 + rrow0] = o;
            }
        }
    }
}

// ------- flash attention v4: balanced 2x2 wave split, gload_lds+swizzle staging -------
__global__ __launch_bounds__(256) void attn4_kernel(const bf16_t* __restrict__ qkv,
                                                    const bf16_t* __restrict__ vt,
                                                    bf16_t* __restrict__ out) {
    const int qb = 31 - blockIdx.x;  // big blocks first
    const int h = blockIdx.y;
    const int tid = threadIdx.x;
    const int w = tid >> 6, lane = tid & 63;
    const int lr = lane & 15, lg = lane >> 4;
    const int qsub = w & 1, ks = w >> 1;
    const int q0 = qb * 32;
    const int qr0 = q0 + qsub * 16;
    const int NT = (q0 >> 6) + 1;

    __shared__ __align__(16) bf16_t Ksh[2][64 * 64];
    __shared__ __align__(16) bf16_t Vsh[2][64 * 64];
    __shared__ bf16_t Ps[4][16][72];
    __shared__ float Osh[2][16][64];
    __shared__ float mlsh[2][2][16];

    bf16x8 aq[2];
    {
        const size_t qoff = (size_t)(qr0 + lr) * 2304 + h * 64;
#pragma unroll
        for (int dt = 0; dt < 2; ++dt) {
            bf16x8 v = *(const bf16x8*)&qkv[qoff + dt * 32 + lg * 8];
#pragma unroll
            for (int i = 0; i < 8; ++i) v[i] = (bf16_t)((float)v[i] * 0.125f);
            aq[dt] = v;
        }
    }

    f32x4 oacc[4];
#pragma unroll
    for (int i = 0; i < 4; ++i) oacc[i] = zero4();
    float mrun[4], lrun[4];
#pragma unroll
    for (int i = 0; i < 4; ++i) {
        mrun[i] = -3.0e38f;
        lrun[i] = 0.f;
    }

    const int st = tid >> 7, tt = tid & 127;
    const int rounds = (NT + 1) >> 1;

    for (int rr = 0; rr < rounds; ++rr) {
        const int skb = 2 * rr + st;
        if (skb < NT) {
            const int k0s = skb * 64;
#pragma unroll
            for (int i = 0; i < 4; ++i) {
                int v = i * 128 + tt;
                int row = v >> 3, cg = v & 7;
                gload16(qkv + (size_t)(k0s + row) * 2304 + 768 + h * 64 +
                            ((cg ^ (row & 7)) << 3),
                        &Ksh[st][v * 8]);
            }
#pragma unroll
            for (int i = 0; i < 4; ++i) {
                int v = i * 128 + tt;
                int row = v >> 3, cg = v & 7;
                gload16(vt + (size_t)(h * 64 + row) * 1024 + k0s + ((cg ^ (row & 7)) << 3),
                        &Vsh[st][v * 8]);
            }
        }
        __syncthreads();

        const int kb = 2 * rr + ks;
        if (kb < NT) {
            const int k0 = kb * 64;
            f32x4 sacc[4];
#pragma unroll
            for (int i = 0; i < 4; ++i) sacc[i] = zero4();
            __builtin_amdgcn_s_setprio(1);
#pragma unroll
            for (int kt = 0; kt < 4; ++kt) {
                const int row = kt * 16 + lr;
#pragma unroll
                for (int dt = 0; dt < 2; ++dt) {
                    bf16x8 bk = *(const bf16x8*)&Ksh[ks][row * 64 +
                                                        ((dt * 32 + lg * 8) ^ ((row & 7) << 3))];
                    sacc[kt] = MFMA16(aq[dt], bk, sacc[kt]);
                }
            }
            __builtin_amdgcn_s_setprio(0);

            if (kb == NT - 1) {
#pragma unroll
                for (int kt = 0; kt < 4; ++kt)
#pragma unroll
                    for (int i = 0; i < 4; ++i)
                        if (k0 + kt * 16 + lr > qr0 + lg * 4 + i) sacc[kt][i] = -3.0e38f;
            }

#pragma unroll
            for (int i = 0; i < 4; ++i) {
                float rmax = fmaxf(fmaxf(sacc[0][i], sacc[1][i]), fmaxf(sacc[2][i], sacc[3][i]));
                rmax = fmaxf(rmax, __shfl_xor(rmax, 1));
                rmax = fmaxf(rmax, __shfl_xor(rmax, 2));
                rmax = fmaxf(rmax, __shfl_xor(rmax, 4));
                rmax = fmaxf(rmax, __shfl_xor(rmax, 8));
                const float mnew = fmaxf(mrun[i], rmax);
                const float sf = __expf(mrun[i] - mnew);
                mrun[i] = mnew;
                float rsum = 0.f;
#pragma unroll
                for (int kt = 0; kt < 4; ++kt) {
                    float p = __expf(sacc[kt][i] - mnew);
                    rsum += p;
                    Ps[w][lg * 4 + i][kt * 16 + lr] = (bf16_t)p;
                }
                rsum += __shfl_xor(rsum, 1);
                rsum += __shfl_xor(rsum, 2);
                rsum += __shfl_xor(rsum, 4);
                rsum += __shfl_xor(rsum, 8);
                lrun[i] = lrun[i] * sf + rsum;
#pragma unroll
                for (int ot = 0; ot < 4; ++ot) oacc[ot][i] *= sf;
            }

            bf16x8 pa0 = *(const bf16x8*)&Ps[w][lr][lg * 8];
            bf16x8 pa1 = *(const bf16x8*)&Ps[w][lr][32 + lg * 8];
            __builtin_amdgcn_s_setprio(1);
#pragma unroll
            for (int ot = 0; ot < 4; ++ot) {
                const int row = ot * 16 + lr;
                bf16x8 bv0 = *(const bf16x8*)&Vsh[ks][row * 64 + ((lg * 8) ^ ((row & 7) << 3))];
                bf16x8 bv1 =
                    *(const bf16x8*)&Vsh[ks][row * 64 + ((32 + lg * 8) ^ ((row & 7) << 3))];
                oacc[ot] = MFMA16(pa0, bv0, oacc[ot]);
                oacc[ot] = MFMA16(pa1, bv1, oacc[ot]);
            }
            __builtin_amdgcn_s_setprio(0);
        }
        __syncthreads();
    }

    if (ks == 1) {
        if (lr == 0) {
#pragma unroll
            for (int i = 0; i < 4; ++i) {
                mlsh[qsub][0][lg * 4 + i] = mrun[i];
                mlsh[qsub][1][lg * 4 + i] = lrun[i];
            }
        }
#pragma unroll
        for (int ot = 0; ot < 4; ++ot)
#pragma unroll
            for (int i = 0; i < 4; ++i) Osh[qsub][lg * 4 + i][ot * 16 + lr] = oacc[ot][i];
    }
    __syncthreads();
    if (ks == 0) {
#pragma unroll
        for (int ot = 0; ot < 4; ++ot)
#pragma unroll
            for (int i = 0; i < 4; ++i) {
                const int row = lg * 4 + i;
                const float m1 = mlsh[qsub][0][row], l1 = mlsh[qsub][1][row];
                const float mm = fmaxf(mrun[i], m1);
                const float fa = __expf(mrun[i] - mm), fb = __expf(m1 - mm);
                const float ll = lrun[i] * fa + l1 * fb;
                const float v = (oacc[ot][i] * fa + Osh[qsub][row][ot * 16 + lr] * fb) / ll;
                out[(size_t)(qr0 + row) * 768 + h * 64 + ot * 16 + lr] = (bf16_t)v;
            }
    }
}

// ---------------- launch ----------------
extern "C" void kernel_launch(void* const* d_in, const int* in_sizes, int n_in, void* d_out,
                              int out_size, void* d_ws, size_t ws_size, hipStream_t stream) {
    const int* ids = (const int*)d_in[0];
    const float* wte = (const float*)d_in[1];
    const float* wpe = (const float*)d_in[2];
    const float* ln1_w = (const float*)d_in[3];
    const float* ln1_b = (const float*)d_in[4];
    const float* qkv_w = (const float*)d_in[5];
    const float* qkv_b = (const float*)d_in[6];
    const float* out_w = (const float*)d_in[7];
    const float* out_b = (const float*)d_in[8];
    const float* ln2_w = (const float*)d_in[9];
    const float* ln2_b = (const float*)d_in[10];
    const float* up_w = (const float*)d_in[11];
    const float* up_b = (const float*)d_in[12];
    const float* down_w = (const float*)d_in[13];
    const float* down_b = (const float*)d_in[14];
    const float* lnf_w = (const float*)d_in[15];
    const float* lnf_b = (const float*)d_in[16];

    char* ws = (char*)d_ws;
    float* x = (float*)(ws + 0);                 // 3 MB
    bf16_t* qkv_bf = (bf16_t*)(ws + 3145728);    // 4.5 MB
    bf16_t* attn_bf = (bf16_t*)(ws + 7864320);   // 1.5 MB
    bf16_t* u_bf = (bf16_t*)(ws + 9437184);      // 6 MB (first half doubles as vt)
    bf16_t* vt = (bf16_t*)(ws + 9437184);        // 1.5 MB; dead before u_bf written
    bf16_t* wqkv_t = (bf16_t*)(ws + 17301504);   // [12][2304][768]
    bf16_t* wout_t = (bf16_t*)(ws + 59768832);   // [12][768][768]
    bf16_t* wup_t = (bf16_t*)(ws + 73924608);    // [12][3072][768]
    bf16_t* wdown_t = (bf16_t*)(ws + 130547712); // [12][768][3072]

    float* outF = (float*)d_out;
    const size_t SD = (size_t)1024 * 768;
    float* out_layers = outF + SD;  // [13][1024][768]

    transpose_cvt<<<dim3(72, 24, 12), 256, 0, stream>>>(qkv_w, wqkv_t, 768, 2304);
    transpose_cvt<<<dim3(24, 24, 12), 256, 0, stream>>>(out_w, wout_t, 768, 768);
    transpose_cvt<<<dim3(96, 24, 12), 256, 0, stream>>>(up_w, wup_t, 768, 3072);
    transpose_cvt<<<dim3(24, 96, 12), 256, 0, stream>>>(down_w, wdown_t, 3072, 768);

    embed_kernel<<<1024, 256, 0, stream>>>(ids, wte, wpe, x, out_layers);

    for (int l = 0; l < 12; ++l) {
        const size_t l768 = (size_t)l * 768;
        // qkv = LN1(x) @ Wqkv + b ; also vt = V^T
        gemm3<64, 64, false, false, true, true, false><<<dim3(16, 36), 256, 0, stream>>>(
            nullptr, x, wqkv_t + (size_t)l * 2304 * 768, qkv_b + (size_t)l * 2304, nullptr,
            ln1_w + l768, ln1_b + l768, nullptr, nullptr, qkv_bf, vt, 2304, 768, 768);
        attn4_kernel<<<dim3(32, 12), 256, 0, stream>>>(qkv_bf, vt, attn_bf);
        // x += attn @ Wout + b
        gemm3<64, 64, false, true, false, false, false><<<dim3(16, 12), 256, 0, stream>>>(
            attn_bf, nullptr, wout_t + (size_t)l * 768 * 768, out_b + l768, x, nullptr,
            nullptr, x, nullptr, nullptr, nullptr, 768, 768, 768);
        // u = gelu(LN2(x) @ Wup + b)
        gemm3<64, 64, true, false, false, true, false><<<dim3(16, 48), 256, 0, stream>>>(
            nullptr, x, wup_t + (size_t)l * 3072 * 768, up_b + (size_t)l * 3072, nullptr,
            ln2_w + l768, ln2_b + l768, nullptr, nullptr, u_bf, nullptr, 3072, 768, 768);
        // x += u @ Wdown + b ; slice = x  (z=1, K=3072)
        gemm3<64, 32, false, true, false, false, true><<<dim3(16, 24), 256, 0, stream>>>(
            u_bf, nullptr, wdown_t + (size_t)l * 768 * 3072, down_b + l768, x, nullptr,
            nullptr, x, out_layers + (size_t)(l + 1) * SD, nullptr, nullptr, 768, 3072, 3072);
    }
    ln_kernel<<<1024, 256, 0, stream>>>(x, lnf_w, lnf_b, outF);
}

// Round 13
// 1143.819 us; speedup vs baseline: 1.4080x; 1.4080x over previous
//
#include <hip/hip_runtime.h>

typedef __bf16 bf16_t;
typedef __bf16 bf16x8 __attribute__((ext_vector_type(8)));
typedef __bf16 bf16x4 __attribute__((ext_vector_type(4)));
typedef float f32x4 __attribute__((ext_vector_type(4)));

#define MFMA16(a, b, c) __builtin_amdgcn_mfma_f32_16x16x32_bf16(a, b, c, 0, 0, 0)

__device__ __forceinline__ f32x4 zero4() {
    f32x4 z = {0.f, 0.f, 0.f, 0.f};
    return z;
}

__device__ __forceinline__ float gelu_f(float v) {
    float u = 0.7978845608028654f * (v + 0.044715f * v * v * v);
    float e = __expf(2.0f * u);
    float th = 1.0f - 2.0f / (e + 1.0f);  // tanh(u), overflow-safe
    return 0.5f * v * (1.0f + th);
}

__device__ __forceinline__ void gload16(const bf16_t* g, bf16_t* l) {
    __builtin_amdgcn_global_load_lds((const __attribute__((address_space(1))) void*)g,
                                     (__attribute__((address_space(3))) void*)l, 16, 0, 0);
}

// ---------------- embedding: x = wte[ids] + wpe; also layers_output[0] ----------------
__global__ __launch_bounds__(256) void embed_kernel(const int* __restrict__ ids,
                                                    const float* __restrict__ wte,
                                                    const float* __restrict__ wpe,
                                                    float* __restrict__ x,
                                                    float* __restrict__ out0) {
    const int s = blockIdx.x;
    const int id = ids[s];
    const size_t base = (size_t)s * 768;
#pragma unroll
    for (int r = 0; r < 3; ++r) {
        int d = threadIdx.x + r * 256;
        float v = wte[(size_t)id * 768 + d] + wpe[base + d];
        x[base + d] = v;
        out0[base + d] = v;
    }
}

// ---------------- layernorm: one row per block ----------------
template <bool BF16OUT>
__global__ __launch_bounds__(256) void ln_kernel(const float* __restrict__ x,
                                                 const float* __restrict__ w,
                                                 const float* __restrict__ b,
                                                 void* __restrict__ outp) {
    const int row = blockIdx.x;
    const int t = threadIdx.x;
    const float* xr = x + (size_t)row * 768;
    float v0 = xr[t], v1 = xr[t + 256], v2 = xr[t + 512];
    float s = v0 + v1 + v2;
    float q = v0 * v0 + v1 * v1 + v2 * v2;
#pragma unroll
    for (int off = 32; off >= 1; off >>= 1) {
        s += __shfl_xor(s, off);
        q += __shfl_xor(q, off);
    }
    __shared__ float sh_s[4], sh_q[4];
    if ((t & 63) == 0) {
        sh_s[t >> 6] = s;
        sh_q[t >> 6] = q;
    }
    __syncthreads();
    s = sh_s[0] + sh_s[1] + sh_s[2] + sh_s[3];
    q = sh_q[0] + sh_q[1] + sh_q[2] + sh_q[3];
    const float mean = s * (1.0f / 768.0f);
    const float var = q * (1.0f / 768.0f) - mean * mean;
    const float rstd = rsqrtf(var + 1e-5f);
    float vv[3] = {v0, v1, v2};
#pragma unroll
    for (int r = 0; r < 3; ++r) {
        int d = t + r * 256;
        float y = (vv[r] - mean) * rstd * w[d] + b[d];
        if (BF16OUT)
            ((bf16_t*)outp)[(size_t)row * 768 + d] = (bf16_t)y;
        else
            ((float*)outp)[(size_t)row * 768 + d] = y;
    }
}

// ------- weight transpose + f32->bf16: src[z][K][N] -> dst[z][N][K], all layers -------
__global__ __launch_bounds__(256) void transpose_cvt(const float* __restrict__ src0,
                                                     bf16_t* __restrict__ dst0, int K, int N) {
    const int l = blockIdx.z;
    const float* src = src0 + (size_t)l * K * N;
    bf16_t* dst = dst0 + (size_t)l * N * K;
    const int n0 = blockIdx.x * 32;
    const int k0 = blockIdx.y * 32;
    __shared__ float tile[32][36];
    const int t = threadIdx.x;
    const int r = t >> 3, c4 = (t & 7) * 4;
    const float4 v = *(const float4*)&src[(size_t)(k0 + r) * N + n0 + c4];
    tile[r][c4 + 0] = v.x;
    tile[r][c4 + 1] = v.y;
    tile[r][c4 + 2] = v.z;
    tile[r][c4 + 3] = v.w;
    __syncthreads();
    bf16x4 o;
    o[0] = (bf16_t)tile[c4 + 0][r];
    o[1] = (bf16_t)tile[c4 + 1][r];
    o[2] = (bf16_t)tile[c4 + 2][r];
    o[3] = (bf16_t)tile[c4 + 3][r];
    *(bf16x4*)&dst[(size_t)(n0 + r) * K + k0 + c4] = o;
}

// --------- GEMM: C[1024,N] = A[1024,LDK] x BT[N,LDK]^T over KLEN (z split) ------------
// 4 waves (2x2), BK=64, global_load_lds staging, XOR-swizzled row-major LDS.
// T3/T4: 3-buffer rotation, prefetch depth 2, raw s_barrier + COUNTED s_waitcnt vmcnt(N).
// T5: setprio(1) around the MFMA compute phase.
// outF2: optional second f32 output (out_layers slice). VT: scatter V^T for attention.
template <int BM, int BN, bool GELU, bool RES, bool VT>
__global__ __launch_bounds__(256) void gemm3(const bf16_t* __restrict__ A,
                                             const bf16_t* __restrict__ BT,
                                             const float* __restrict__ bias,
                                             const float* __restrict__ res,
                                             float* __restrict__ outF,
                                             float* __restrict__ outF2,
                                             bf16_t* __restrict__ outB,
                                             bf16_t* __restrict__ vt, int N, int LDK,
                                             int KLEN) {
    constexpr int MW = BM / 32, NW = BN / 32;
    constexpr int TILE = (BM + BN) * 64;
    constexpr int LOADS = (BM + BN) / 32;  // gload16s per thread per stage
    __shared__ __align__(16) bf16_t lds[3 * TILE];
    const int tid = threadIdx.x;
    const int lane = tid & 63, wv = tid >> 6, wm = wv >> 1, wn = wv & 1;
    const int lr = lane & 15, lg = lane >> 4;
    const int m0 = blockIdx.x * BM, n0 = blockIdx.y * BN;
    const bf16_t* Ap = A + (size_t)m0 * LDK + (size_t)blockIdx.z * KLEN;
    const bf16_t* Bp = BT + (size_t)n0 * LDK + (size_t)blockIdx.z * KLEN;

    f32x4 acc[MW][NW];
#pragma unroll
    for (int i = 0; i < MW; ++i)
#pragma unroll
        for (int j = 0; j < NW; ++j) acc[i][j] = zero4();

    const int KT = KLEN >> 6;

    auto stage = [&](int buf, int kt) {
        bf16_t* Ad = lds + buf * TILE;
        bf16_t* Bd = Ad + BM * 64;
#pragma unroll
        for (int i = 0; i < BM / 32; ++i) {
            int v = i * 256 + tid;
            int row = v >> 3, cg = v & 7;
            gload16(Ap + (size_t)row * LDK + kt * 64 + ((cg ^ (row & 7)) << 3), Ad + v * 8);
        }
#pragma unroll
        for (int i = 0; i < BN / 32; ++i) {
            int v = i * 256 + tid;
            int row = v >> 3, cg = v & 7;
            gload16(Bp + (size_t)row * LDK + kt * 64 + ((cg ^ (row & 7)) << 3), Bd + v * 8);
        }
    };

    stage(0, 0);
    stage(1, 1);  // KT >= 12 always here
    int buf = 0;
    for (int kt = 0; kt < KT; ++kt) {
        // wait for tile kt's loads only; keep tile kt+1's in flight across the barrier
        if (kt + 1 < KT) {
            if constexpr (LOADS == 4)
                asm volatile("s_waitcnt vmcnt(4)" ::: "memory");
            else
                asm volatile("s_waitcnt vmcnt(3)" ::: "memory");
        } else {
            asm volatile("s_waitcnt vmcnt(0)" ::: "memory");
        }
        __builtin_amdgcn_s_barrier();
        if (kt + 2 < KT) stage((kt + 2) % 3, kt + 2);
        const bf16_t* Ab = lds + buf * TILE;
        const bf16_t* Bb = Ab + BM * 64;
        __builtin_amdgcn_s_setprio(1);  // T5
#pragma unroll
        for (int c = 0; c < 2; ++c) {
            bf16x8 af[MW], bfr[NW];
#pragma unroll
            for (int i = 0; i < MW; ++i) {
                int row = wm * (BM / 2) + i * 16 + lr;
                af[i] = *(const bf16x8*)&Ab[row * 64 + ((c * 32 + lg * 8) ^ ((row & 7) << 3))];
            }
#pragma unroll
            for (int j = 0; j < NW; ++j) {
                int row = wn * (BN / 2) + j * 16 + lr;
                bfr[j] = *(const bf16x8*)&Bb[row * 64 + ((c * 32 + lg * 8) ^ ((row & 7) << 3))];
            }
#pragma unroll
            for (int i = 0; i < MW; ++i)
#pragma unroll
                for (int j = 0; j < NW; ++j) acc[i][j] = MFMA16(af[i], bfr[j], acc[i][j]);
        }
        __builtin_amdgcn_s_setprio(0);
        buf = (buf + 1) % 3;
    }

    float* o1 = outF ? outF + (size_t)blockIdx.z * ((size_t)1024 * N) : nullptr;
    // epilogue: C/D layout col = lane&15, row = (lane>>4)*4 + reg
#pragma unroll
    for (int i = 0; i < MW; ++i) {
#pragma unroll
        for (int j = 0; j < NW; ++j) {
            const int col = n0 + wn * (BN / 2) + j * 16 + lr;
            const float bc = bias ? bias[col] : 0.f;
            float vr[4];
#pragma unroll
            for (int ii = 0; ii < 4; ++ii) {
                const int rrow = m0 + wm * (BM / 2) + i * 16 + lg * 4 + ii;
                float v = acc[i][j][ii] + bc;
                if (GELU) v = gelu_f(v);
                if (RES) v += res[(size_t)rrow * N + col];
                if (o1) o1[(size_t)rrow * N + col] = v;
                if (outF2) outF2[(size_t)rrow * N + col] = v;
                if (outB) outB[(size_t)rrow * N + col] = (bf16_t)v;
                vr[ii] = v;
            }
            if (VT && col >= 1536) {  // transposed V: vt[d'][seq], 4 consecutive rows
                const int rrow0 = m0 + wm * (BM / 2) + i * 16 + lg * 4;
                bf16x4 o;
#pragma unroll
                for (int ii = 0; ii < 4; ++ii) o[ii] = (bf16_t)vr[ii];
                *(bf16x4*)&vt[(size_t)(col - 1536) * 1024 + rrow0] = o;
            }
        }
    }
}

// ------- flash attention v4: balanced 2x2 wave split, gload_lds+swizzle staging -------
__global__ __launch_bounds__(256) void attn4_kernel(const bf16_t* __restrict__ qkv,
                                                    const bf16_t* __restrict__ vt,
                                                    bf16_t* __restrict__ out) {
    const int qb = 31 - blockIdx.x;  // big blocks first
    const int h = blockIdx.y;
    const int tid = threadIdx.x;
    const int w = tid >> 6, lane = tid & 63;
    const int lr = lane & 15, lg = lane >> 4;
    const int qsub = w & 1, ks = w >> 1;
    const int q0 = qb * 32;
    const int qr0 = q0 + qsub * 16;
    const int NT = (q0 >> 6) + 1;

    __shared__ __align__(16) bf16_t Ksh[2][64 * 64];
    __shared__ __align__(16) bf16_t Vsh[2][64 * 64];
    __shared__ bf16_t Ps[4][16][72];
    __shared__ float Osh[2][16][64];
    __shared__ float mlsh[2][2][16];

    bf16x8 aq[2];
    {
        const size_t qoff = (size_t)(qr0 + lr) * 2304 + h * 64;
#pragma unroll
        for (int dt = 0; dt < 2; ++dt) {
            bf16x8 v = *(const bf16x8*)&qkv[qoff + dt * 32 + lg * 8];
#pragma unroll
            for (int i = 0; i < 8; ++i) v[i] = (bf16_t)((float)v[i] * 0.125f);
            aq[dt] = v;
        }
    }

    f32x4 oacc[4];
#pragma unroll
    for (int i = 0; i < 4; ++i) oacc[i] = zero4();
    float mrun[4], lrun[4];
#pragma unroll
    for (int i = 0; i < 4; ++i) {
        mrun[i] = -3.0e38f;
        lrun[i] = 0.f;
    }

    const int st = tid >> 7, tt = tid & 127;
    const int rounds = (NT + 1) >> 1;

    for (int rr = 0; rr < rounds; ++rr) {
        const int skb = 2 * rr + st;
        if (skb < NT) {
            const int k0s = skb * 64;
#pragma unroll
            for (int i = 0; i < 4; ++i) {
                int v = i * 128 + tt;
                int row = v >> 3, cg = v & 7;
                gload16(qkv + (size_t)(k0s + row) * 2304 + 768 + h * 64 +
                            ((cg ^ (row & 7)) << 3),
                        &Ksh[st][v * 8]);
            }
#pragma unroll
            for (int i = 0; i < 4; ++i) {
                int v = i * 128 + tt;
                int row = v >> 3, cg = v & 7;
                gload16(vt + (size_t)(h * 64 + row) * 1024 + k0s + ((cg ^ (row & 7)) << 3),
                        &Vsh[st][v * 8]);
            }
        }
        __syncthreads();

        const int kb = 2 * rr + ks;
        if (kb < NT) {
            const int k0 = kb * 64;
            f32x4 sacc[4];
#pragma unroll
            for (int i = 0; i < 4; ++i) sacc[i] = zero4();
            __builtin_amdgcn_s_setprio(1);
#pragma unroll
            for (int kt = 0; kt < 4; ++kt) {
                const int row = kt * 16 + lr;
#pragma unroll
                for (int dt = 0; dt < 2; ++dt) {
                    bf16x8 bk = *(const bf16x8*)&Ksh[ks][row * 64 +
                                                        ((dt * 32 + lg * 8) ^ ((row & 7) << 3))];
                    sacc[kt] = MFMA16(aq[dt], bk, sacc[kt]);
                }
            }
            __builtin_amdgcn_s_setprio(0);

            if (kb == NT - 1) {
#pragma unroll
                for (int kt = 0; kt < 4; ++kt)
#pragma unroll
                    for (int i = 0; i < 4; ++i)
                        if (k0 + kt * 16 + lr > qr0 + lg * 4 + i) sacc[kt][i] = -3.0e38f;
            }

#pragma unroll
            for (int i = 0; i < 4; ++i) {
                float rmax = fmaxf(fmaxf(sacc[0][i], sacc[1][i]), fmaxf(sacc[2][i], sacc[3][i]));
                rmax = fmaxf(rmax, __shfl_xor(rmax, 1));
                rmax = fmaxf(rmax, __shfl_xor(rmax, 2));
                rmax = fmaxf(rmax, __shfl_xor(rmax, 4));
                rmax = fmaxf(rmax, __shfl_xor(rmax, 8));
                const float mnew = fmaxf(mrun[i], rmax);
                const float sf = __expf(mrun[i] - mnew);
                mrun[i] = mnew;
                float rsum = 0.f;
#pragma unroll
                for (int kt = 0; kt < 4; ++kt) {
                    float p = __expf(sacc[kt][i] - mnew);
                    rsum += p;
                    Ps[w][lg * 4 + i][kt * 16 + lr] = (bf16_t)p;
                }
                rsum += __shfl_xor(rsum, 1);
                rsum += __shfl_xor(rsum, 2);
                rsum += __shfl_xor(rsum, 4);
                rsum += __shfl_xor(rsum, 8);
                lrun[i] = lrun[i] * sf + rsum;
#pragma unroll
                for (int ot = 0; ot < 4; ++ot) oacc[ot][i] *= sf;
            }

            bf16x8 pa0 = *(const bf16x8*)&Ps[w][lr][lg * 8];
            bf16x8 pa1 = *(const bf16x8*)&Ps[w][lr][32 + lg * 8];
            __builtin_amdgcn_s_setprio(1);
#pragma unroll
            for (int ot = 0; ot < 4; ++ot) {
                const int row = ot * 16 + lr;
                bf16x8 bv0 = *(const bf16x8*)&Vsh[ks][row * 64 + ((lg * 8) ^ ((row & 7) << 3))];
                bf16x8 bv1 =
                    *(const bf16x8*)&Vsh[ks][row * 64 + ((32 + lg * 8) ^ ((row & 7) << 3))];
                oacc[ot] = MFMA16(pa0, bv0, oacc[ot]);
                oacc[ot] = MFMA16(pa1, bv1, oacc[ot]);
            }
            __builtin_amdgcn_s_setprio(0);
        }
        __syncthreads();
    }

    if (ks == 1) {
        if (lr == 0) {
#pragma unroll
            for (int i = 0; i < 4; ++i) {
                mlsh[qsub][0][lg * 4 + i] = mrun[i];
                mlsh[qsub][1][lg * 4 + i] = lrun[i];
            }
        }
#pragma unroll
        for (int ot = 0; ot < 4; ++ot)
#pragma unroll
            for (int i = 0; i < 4; ++i) Osh[qsub][lg * 4 + i][ot * 16 + lr] = oacc[ot][i];
    }
    __syncthreads();
    if (ks == 0) {
#pragma unroll
        for (int ot = 0; ot < 4; ++ot)
#pragma unroll
            for (int i = 0; i < 4; ++i) {
                const int row = lg * 4 + i;
                const float m1 = mlsh[qsub][0][row], l1 = mlsh[qsub][1][row];
                const float mm = fmaxf(mrun[i], m1);
                const float fa = __expf(mrun[i] - mm), fb = __expf(m1 - mm);
                const float ll = lrun[i] * fa + l1 * fb;
                const float v = (oacc[ot][i] * fa + Osh[qsub][row][ot * 16 + lr] * fb) / ll;
                out[(size_t)(qr0 + row) * 768 + h * 64 + ot * 16 + lr] = (bf16_t)v;
            }
    }
}

// ---------------- launch ----------------
extern "C" void kernel_launch(void* const* d_in, const int* in_sizes, int n_in, void* d_out,
                              int out_size, void* d_ws, size_t ws_size, hipStream_t stream) {
    const int* ids = (const int*)d_in[0];
    const float* wte = (const float*)d_in[1];
    const float* wpe = (const float*)d_in[2];
    const float* ln1_w = (const float*)d_in[3];
    const float* ln1_b = (const float*)d_in[4];
    const float* qkv_w = (const float*)d_in[5];
    const float* qkv_b = (const float*)d_in[6];
    const float* out_w = (const float*)d_in[7];
    const float* out_b = (const float*)d_in[8];
    const float* ln2_w = (const float*)d_in[9];
    const float* ln2_b = (const float*)d_in[10];
    const float* up_w = (const float*)d_in[11];
    const float* up_b = (const float*)d_in[12];
    const float* down_w = (const float*)d_in[13];
    const float* down_b = (const float*)d_in[14];
    const float* lnf_w = (const float*)d_in[15];
    const float* lnf_b = (const float*)d_in[16];

    char* ws = (char*)d_ws;
    float* x = (float*)(ws + 0);                 // 3 MB
    bf16_t* a_bf = (bf16_t*)(ws + 3145728);      // 1.5 MB
    bf16_t* qkv_bf = (bf16_t*)(ws + 4718592);    // 4.5 MB
    bf16_t* attn_bf = (bf16_t*)(ws + 9437184);   // 1.5 MB
    bf16_t* u_bf = (bf16_t*)(ws + 11010048);     // 6 MB (first half doubles as vt)
    bf16_t* vt = (bf16_t*)(ws + 11010048);       // 1.5 MB; dead before u_bf written
    bf16_t* wqkv_t = (bf16_t*)(ws + 17301504);   // [12][2304][768]
    bf16_t* wout_t = (bf16_t*)(ws + 59768832);   // [12][768][768]
    bf16_t* wup_t = (bf16_t*)(ws + 73924608);    // [12][3072][768]
    bf16_t* wdown_t = (bf16_t*)(ws + 130547712); // [12][768][3072]

    float* outF = (float*)d_out;
    const size_t SD = (size_t)1024 * 768;
    float* out_layers = outF + SD;  // [13][1024][768]

    transpose_cvt<<<dim3(72, 24, 12), 256, 0, stream>>>(qkv_w, wqkv_t, 768, 2304);
    transpose_cvt<<<dim3(24, 24, 12), 256, 0, stream>>>(out_w, wout_t, 768, 768);
    transpose_cvt<<<dim3(96, 24, 12), 256, 0, stream>>>(up_w, wup_t, 768, 3072);
    transpose_cvt<<<dim3(24, 96, 12), 256, 0, stream>>>(down_w, wdown_t, 3072, 768);

    embed_kernel<<<1024, 256, 0, stream>>>(ids, wte, wpe, x, out_layers);

    for (int l = 0; l < 12; ++l) {
        const size_t l768 = (size_t)l * 768;
        // a_bf = LN1(x)
        ln_kernel<true><<<1024, 256, 0, stream>>>(x, ln1_w + l768, ln1_b + l768, a_bf);
        // qkv = a_bf @ Wqkv + b ; vt = V^T
        gemm3<64, 64, false, false, true><<<dim3(16, 36), 256, 0, stream>>>(
            a_bf, wqkv_t + (size_t)l * 2304 * 768, qkv_b + (size_t)l * 2304, nullptr, nullptr,
            nullptr, qkv_bf, vt, 2304, 768, 768);
        attn4_kernel<<<dim3(32, 12), 256, 0, stream>>>(qkv_bf, vt, attn_bf);
        // x += attn @ Wout + b
        gemm3<64, 64, false, true, false><<<dim3(16, 12), 256, 0, stream>>>(
            attn_bf, wout_t + (size_t)l * 768 * 768, out_b + l768, x, x, nullptr, nullptr,
            nullptr, 768, 768, 768);
        // a_bf = LN2(x)
        ln_kernel<true><<<1024, 256, 0, stream>>>(x, ln2_w + l768, ln2_b + l768, a_bf);
        // u = gelu(a_bf @ Wup + b)
        gemm3<64, 64, true, false, false><<<dim3(16, 48), 256, 0, stream>>>(
            a_bf, wup_t + (size_t)l * 3072 * 768, up_b + (size_t)l * 3072, nullptr, nullptr,
            nullptr, u_bf, nullptr, 3072, 768, 768);
        // x += u @ Wdown + b ; out_layers slice = x   (z=1, full K=3072)
        gemm3<64, 32, false, true, false><<<dim3(16, 24), 256, 0, stream>>>(
            u_bf, wdown_t + (size_t)l * 768 * 3072, down_b + l768, x, x,
            out_layers + (size_t)(l + 1) * SD, nullptr, nullptr, 768, 3072, 3072);
    }
    ln_kernel<false><<<1024, 256, 0, stream>>>(x, lnf_w, lnf_b, outF);
}

// Round 14
// 1082.813 us; speedup vs baseline: 1.4873x; 1.0563x over previous
//
#include <hip/hip_runtime.h>

typedef __bf16 bf16_t;
typedef __bf16 bf16x8 __attribute__((ext_vector_type(8)));
typedef __bf16 bf16x4 __attribute__((ext_vector_type(4)));
typedef float f32x4 __attribute__((ext_vector_type(4)));

#define MFMA16(a, b, c) __builtin_amdgcn_mfma_f32_16x16x32_bf16(a, b, c, 0, 0, 0)

__device__ __forceinline__ f32x4 zero4() {
    f32x4 z = {0.f, 0.f, 0.f, 0.f};
    return z;
}

__device__ __forceinline__ float gelu_f(float v) {
    float u = 0.7978845608028654f * (v + 0.044715f * v * v * v);
    float e = __expf(2.0f * u);
    float th = 1.0f - 2.0f / (e + 1.0f);  // tanh(u), overflow-safe
    return 0.5f * v * (1.0f + th);
}

__device__ __forceinline__ void gload16(const bf16_t* g, bf16_t* l) {
    __builtin_amdgcn_global_load_lds((const __attribute__((address_space(1))) void*)g,
                                     (__attribute__((address_space(3))) void*)l, 16, 0, 0);
}

// ---------------- embedding: x = wte[ids] + wpe; also layers_output[0] ----------------
__global__ __launch_bounds__(256) void embed_kernel(const int* __restrict__ ids,
                                                    const float* __restrict__ wte,
                                                    const float* __restrict__ wpe,
                                                    float* __restrict__ x,
                                                    float* __restrict__ out0) {
    const int s = blockIdx.x;
    const int id = ids[s];
    const size_t base = (size_t)s * 768;
#pragma unroll
    for (int r = 0; r < 3; ++r) {
        int d = threadIdx.x + r * 256;
        float v = wte[(size_t)id * 768 + d] + wpe[base + d];
        x[base + d] = v;
        out0[base + d] = v;
    }
}

// ---------------- layernorm: one row per block ----------------
template <bool BF16OUT>
__global__ __launch_bounds__(256) void ln_kernel(const float* __restrict__ x,
                                                 const float* __restrict__ w,
                                                 const float* __restrict__ b,
                                                 void* __restrict__ outp) {
    const int row = blockIdx.x;
    const int t = threadIdx.x;
    const float* xr = x + (size_t)row * 768;
    float v0 = xr[t], v1 = xr[t + 256], v2 = xr[t + 512];
    float s = v0 + v1 + v2;
    float q = v0 * v0 + v1 * v1 + v2 * v2;
#pragma unroll
    for (int off = 32; off >= 1; off >>= 1) {
        s += __shfl_xor(s, off);
        q += __shfl_xor(q, off);
    }
    __shared__ float sh_s[4], sh_q[4];
    if ((t & 63) == 0) {
        sh_s[t >> 6] = s;
        sh_q[t >> 6] = q;
    }
    __syncthreads();
    s = sh_s[0] + sh_s[1] + sh_s[2] + sh_s[3];
    q = sh_q[0] + sh_q[1] + sh_q[2] + sh_q[3];
    const float mean = s * (1.0f / 768.0f);
    const float var = q * (1.0f / 768.0f) - mean * mean;
    const float rstd = rsqrtf(var + 1e-5f);
    float vv[3] = {v0, v1, v2};
#pragma unroll
    for (int r = 0; r < 3; ++r) {
        int d = t + r * 256;
        float y = (vv[r] - mean) * rstd * w[d] + b[d];
        if (BF16OUT)
            ((bf16_t*)outp)[(size_t)row * 768 + d] = (bf16_t)y;
        else
            ((float*)outp)[(size_t)row * 768 + d] = y;
    }
}

// ------- fused: x += p0 + p1 + down_bias; write out_layers slice; LN -> lnout ---------
template <bool FINAL>
__global__ __launch_bounds__(256) void ln_reduce(const float* __restrict__ p0,
                                                 const float* __restrict__ p1,
                                                 const float* __restrict__ db,
                                                 float* __restrict__ x,
                                                 float* __restrict__ slice,
                                                 void* __restrict__ lnout,
                                                 const float* __restrict__ w,
                                                 const float* __restrict__ b) {
    const int row = blockIdx.x;
    const int t = threadIdx.x;
    const size_t base = (size_t)row * 768;
    float vv[3];
#pragma unroll
    for (int r = 0; r < 3; ++r) {
        int d = t + r * 256;
        float v = x[base + d] + p0[base + d] + p1[base + d] + db[d];
        vv[r] = v;
        x[base + d] = v;
        slice[base + d] = v;
    }
    float s = vv[0] + vv[1] + vv[2];
    float q = vv[0] * vv[0] + vv[1] * vv[1] + vv[2] * vv[2];
#pragma unroll
    for (int off = 32; off >= 1; off >>= 1) {
        s += __shfl_xor(s, off);
        q += __shfl_xor(q, off);
    }
    __shared__ float sh_s[4], sh_q[4];
    if ((t & 63) == 0) {
        sh_s[t >> 6] = s;
        sh_q[t >> 6] = q;
    }
    __syncthreads();
    s = sh_s[0] + sh_s[1] + sh_s[2] + sh_s[3];
    q = sh_q[0] + sh_q[1] + sh_q[2] + sh_q[3];
    const float mean = s * (1.0f / 768.0f);
    const float var = q * (1.0f / 768.0f) - mean * mean;
    const float rstd = rsqrtf(var + 1e-5f);
#pragma unroll
    for (int r = 0; r < 3; ++r) {
        int d = t + r * 256;
        float y = (vv[r] - mean) * rstd * w[d] + b[d];
        if (FINAL)
            ((float*)lnout)[base + d] = y;
        else
            ((bf16_t*)lnout)[base + d] = (bf16_t)y;
    }
}

// ------- weight transpose + f32->bf16: src[z][K][N] -> dst[z][N][K], all layers -------
__global__ __launch_bounds__(256) void transpose_cvt(const float* __restrict__ src0,
                                                     bf16_t* __restrict__ dst0, int K, int N) {
    const int l = blockIdx.z;
    const float* src = src0 + (size_t)l * K * N;
    bf16_t* dst = dst0 + (size_t)l * N * K;
    const int n0 = blockIdx.x * 32;
    const int k0 = blockIdx.y * 32;
    __shared__ float tile[32][36];
    const int t = threadIdx.x;
    const int r = t >> 3, c4 = (t & 7) * 4;
    const float4 v = *(const float4*)&src[(size_t)(k0 + r) * N + n0 + c4];
    tile[r][c4 + 0] = v.x;
    tile[r][c4 + 1] = v.y;
    tile[r][c4 + 2] = v.z;
    tile[r][c4 + 3] = v.w;
    __syncthreads();
    bf16x4 o;
    o[0] = (bf16_t)tile[c4 + 0][r];
    o[1] = (bf16_t)tile[c4 + 1][r];
    o[2] = (bf16_t)tile[c4 + 2][r];
    o[3] = (bf16_t)tile[c4 + 3][r];
    *(bf16x4*)&dst[(size_t)(n0 + r) * K + k0 + c4] = o;
}

// --------- GEMM: C[1024,N] = A[1024,LDK] x BT[N,LDK]^T over KLEN (z split) ------------
// 4 waves (2x2), BK=64, global_load_lds staging, XOR-swizzled row-major LDS.
// T3/T4: 3-buffer rotation, prefetch depth 2, raw s_barrier + COUNTED s_waitcnt vmcnt(N).
// T5: setprio(1) around the MFMA compute phase.
// VT: also scatter transposed V (cols>=1536 of qkv) to vt[768][1024].
template <int BM, int BN, bool GELU, bool RES, bool VT>
__global__ __launch_bounds__(256) void gemm3(const bf16_t* __restrict__ A,
                                             const bf16_t* __restrict__ BT,
                                             const float* __restrict__ bias,
                                             const float* __restrict__ res,
                                             float* __restrict__ outF,
                                             bf16_t* __restrict__ outB,
                                             bf16_t* __restrict__ vt, int N, int LDK,
                                             int KLEN) {
    constexpr int MW = BM / 32, NW = BN / 32;
    constexpr int TILE = (BM + BN) * 64;
    constexpr int LOADS = (BM + BN) / 32;  // gload16s per thread per stage
    __shared__ __align__(16) bf16_t lds[3 * TILE];
    const int tid = threadIdx.x;
    const int lane = tid & 63, wv = tid >> 6, wm = wv >> 1, wn = wv & 1;
    const int lr = lane & 15, lg = lane >> 4;
    const int m0 = blockIdx.x * BM, n0 = blockIdx.y * BN;
    const bf16_t* Ap = A + (size_t)m0 * LDK + (size_t)blockIdx.z * KLEN;
    const bf16_t* Bp = BT + (size_t)n0 * LDK + (size_t)blockIdx.z * KLEN;

    f32x4 acc[MW][NW];
#pragma unroll
    for (int i = 0; i < MW; ++i)
#pragma unroll
        for (int j = 0; j < NW; ++j) acc[i][j] = zero4();

    const int KT = KLEN >> 6;

    auto stage = [&](int buf, int kt) {
        bf16_t* Ad = lds + buf * TILE;
        bf16_t* Bd = Ad + BM * 64;
#pragma unroll
        for (int i = 0; i < BM / 32; ++i) {
            int v = i * 256 + tid;
            int row = v >> 3, cg = v & 7;
            gload16(Ap + (size_t)row * LDK + kt * 64 + ((cg ^ (row & 7)) << 3), Ad + v * 8);
        }
#pragma unroll
        for (int i = 0; i < BN / 32; ++i) {
            int v = i * 256 + tid;
            int row = v >> 3, cg = v & 7;
            gload16(Bp + (size_t)row * LDK + kt * 64 + ((cg ^ (row & 7)) << 3), Bd + v * 8);
        }
    };

    stage(0, 0);
    stage(1, 1);  // KT >= 12 always here
    int buf = 0;
    for (int kt = 0; kt < KT; ++kt) {
        // wait for tile kt's loads only; keep tile kt+1's in flight across the barrier
        if (kt + 1 < KT) {
            if constexpr (LOADS == 4)
                asm volatile("s_waitcnt vmcnt(4)" ::: "memory");
            else
                asm volatile("s_waitcnt vmcnt(3)" ::: "memory");
        } else {
            asm volatile("s_waitcnt vmcnt(0)" ::: "memory");
        }
        __builtin_amdgcn_s_barrier();
        if (kt + 2 < KT) stage((kt + 2) % 3, kt + 2);
        const bf16_t* Ab = lds + buf * TILE;
        const bf16_t* Bb = Ab + BM * 64;
        __builtin_amdgcn_s_setprio(1);  // T5
#pragma unroll
        for (int c = 0; c < 2; ++c) {
            bf16x8 af[MW], bfr[NW];
#pragma unroll
            for (int i = 0; i < MW; ++i) {
                int row = wm * (BM / 2) + i * 16 + lr;
                af[i] = *(const bf16x8*)&Ab[row * 64 + ((c * 32 + lg * 8) ^ ((row & 7) << 3))];
            }
#pragma unroll
            for (int j = 0; j < NW; ++j) {
                int row = wn * (BN / 2) + j * 16 + lr;
                bfr[j] = *(const bf16x8*)&Bb[row * 64 + ((c * 32 + lg * 8) ^ ((row & 7) << 3))];
            }
#pragma unroll
            for (int i = 0; i < MW; ++i)
#pragma unroll
                for (int j = 0; j < NW; ++j) acc[i][j] = MFMA16(af[i], bfr[j], acc[i][j]);
        }
        __builtin_amdgcn_s_setprio(0);
        buf = (buf + 1) % 3;
    }

    float* o1 = outF ? outF + (size_t)blockIdx.z * ((size_t)1024 * N) : nullptr;
    // epilogue: C/D layout col = lane&15, row = (lane>>4)*4 + reg
#pragma unroll
    for (int i = 0; i < MW; ++i) {
#pragma unroll
        for (int j = 0; j < NW; ++j) {
            const int col = n0 + wn * (BN / 2) + j * 16 + lr;
            const float bc = bias ? bias[col] : 0.f;
            float vr[4];
#pragma unroll
            for (int ii = 0; ii < 4; ++ii) {
                const int rrow = m0 + wm * (BM / 2) + i * 16 + lg * 4 + ii;
                float v = acc[i][j][ii] + bc;
                if (GELU) v = gelu_f(v);
                if (RES) v += res[(size_t)rrow * N + col];
                if (o1) o1[(size_t)rrow * N + col] = v;
                if (outB) outB[(size_t)rrow * N + col] = (bf16_t)v;
                vr[ii] = v;
            }
            if (VT && col >= 1536) {  // transposed V: vt[d'][seq], 4 consecutive rows
                const int rrow0 = m0 + wm * (BM / 2) + i * 16 + lg * 4;
                bf16x4 o;
#pragma unroll
                for (int ii = 0; ii < 4; ++ii) o[ii] = (bf16_t)vr[ii];
                *(bf16x4*)&vt[(size_t)(col - 1536) * 1024 + rrow0] = o;
            }
        }
    }
}

// ------- flash attention v4: balanced 2x2 wave split, gload_lds+swizzle staging -------
__global__ __launch_bounds__(256) void attn4_kernel(const bf16_t* __restrict__ qkv,
                                                    const bf16_t* __restrict__ vt,
                                                    bf16_t* __restrict__ out) {
    const int qb = 31 - blockIdx.x;  // big blocks first
    const int h = blockIdx.y;
    const int tid = threadIdx.x;
    const int w = tid >> 6, lane = tid & 63;
    const int lr = lane & 15, lg = lane >> 4;
    const int qsub = w & 1, ks = w >> 1;
    const int q0 = qb * 32;
    const int qr0 = q0 + qsub * 16;
    const int NT = (q0 >> 6) + 1;

    __shared__ __align__(16) bf16_t Ksh[2][64 * 64];
    __shared__ __align__(16) bf16_t Vsh[2][64 * 64];
    __shared__ bf16_t Ps[4][16][72];
    __shared__ float Osh[2][16][64];
    __shared__ float mlsh[2][2][16];

    bf16x8 aq[2];
    {
        const size_t qoff = (size_t)(qr0 + lr) * 2304 + h * 64;
#pragma unroll
        for (int dt = 0; dt < 2; ++dt) {
            bf16x8 v = *(const bf16x8*)&qkv[qoff + dt * 32 + lg * 8];
#pragma unroll
            for (int i = 0; i < 8; ++i) v[i] = (bf16_t)((float)v[i] * 0.125f);
            aq[dt] = v;
        }
    }

    f32x4 oacc[4];
#pragma unroll
    for (int i = 0; i < 4; ++i) oacc[i] = zero4();
    float mrun[4], lrun[4];
#pragma unroll
    for (int i = 0; i < 4; ++i) {
        mrun[i] = -3.0e38f;
        lrun[i] = 0.f;
    }

    const int st = tid >> 7, tt = tid & 127;
    const int rounds = (NT + 1) >> 1;

    for (int rr = 0; rr < rounds; ++rr) {
        const int skb = 2 * rr + st;
        if (skb < NT) {
            const int k0s = skb * 64;
#pragma unroll
            for (int i = 0; i < 4; ++i) {
                int v = i * 128 + tt;
                int row = v >> 3, cg = v & 7;
                gload16(qkv + (size_t)(k0s + row) * 2304 + 768 + h * 64 +
                            ((cg ^ (row & 7)) << 3),
                        &Ksh[st][v * 8]);
            }
#pragma unroll
            for (int i = 0; i < 4; ++i) {
                int v = i * 128 + tt;
                int row = v >> 3, cg = v & 7;
                gload16(vt + (size_t)(h * 64 + row) * 1024 + k0s + ((cg ^ (row & 7)) << 3),
                        &Vsh[st][v * 8]);
            }
        }
        __syncthreads();

        const int kb = 2 * rr + ks;
        if (kb < NT) {
            const int k0 = kb * 64;
            f32x4 sacc[4];
#pragma unroll
            for (int i = 0; i < 4; ++i) sacc[i] = zero4();
            __builtin_amdgcn_s_setprio(1);
#pragma unroll
            for (int kt = 0; kt < 4; ++kt) {
                const int row = kt * 16 + lr;
#pragma unroll
                for (int dt = 0; dt < 2; ++dt) {
                    bf16x8 bk = *(const bf16x8*)&Ksh[ks][row * 64 +
                                                        ((dt * 32 + lg * 8) ^ ((row & 7) << 3))];
                    sacc[kt] = MFMA16(aq[dt], bk, sacc[kt]);
                }
            }
            __builtin_amdgcn_s_setprio(0);

            if (kb == NT - 1) {
#pragma unroll
                for (int kt = 0; kt < 4; ++kt)
#pragma unroll
                    for (int i = 0; i < 4; ++i)
                        if (k0 + kt * 16 + lr > qr0 + lg * 4 + i) sacc[kt][i] = -3.0e38f;
            }

#pragma unroll
            for (int i = 0; i < 4; ++i) {
                float rmax = fmaxf(fmaxf(sacc[0][i], sacc[1][i]), fmaxf(sacc[2][i], sacc[3][i]));
                rmax = fmaxf(rmax, __shfl_xor(rmax, 1));
                rmax = fmaxf(rmax, __shfl_xor(rmax, 2));
                rmax = fmaxf(rmax, __shfl_xor(rmax, 4));
                rmax = fmaxf(rmax, __shfl_xor(rmax, 8));
                const float mnew = fmaxf(mrun[i], rmax);
                const float sf = __expf(mrun[i] - mnew);
                mrun[i] = mnew;
                float rsum = 0.f;
#pragma unroll
                for (int kt = 0; kt < 4; ++kt) {
                    float p = __expf(sacc[kt][i] - mnew);
                    rsum += p;
                    Ps[w][lg * 4 + i][kt * 16 + lr] = (bf16_t)p;
                }
                rsum += __shfl_xor(rsum, 1);
                rsum += __shfl_xor(rsum, 2);
                rsum += __shfl_xor(rsum, 4);
                rsum += __shfl_xor(rsum, 8);
                lrun[i] = lrun[i] * sf + rsum;
#pragma unroll
                for (int ot = 0; ot < 4; ++ot) oacc[ot][i] *= sf;
            }

            bf16x8 pa0 = *(const bf16x8*)&Ps[w][lr][lg * 8];
            bf16x8 pa1 = *(const bf16x8*)&Ps[w][lr][32 + lg * 8];
            __builtin_amdgcn_s_setprio(1);
#pragma unroll
            for (int ot = 0; ot < 4; ++ot) {
                const int row = ot * 16 + lr;
                bf16x8 bv0 = *(const bf16x8*)&Vsh[ks][row * 64 + ((lg * 8) ^ ((row & 7) << 3))];
                bf16x8 bv1 =
                    *(const bf16x8*)&Vsh[ks][row * 64 + ((32 + lg * 8) ^ ((row & 7) << 3))];
                oacc[ot] = MFMA16(pa0, bv0, oacc[ot]);
                oacc[ot] = MFMA16(pa1, bv1, oacc[ot]);
            }
            __builtin_amdgcn_s_setprio(0);
        }
        __syncthreads();
    }

    if (ks == 1) {
        if (lr == 0) {
#pragma unroll
            for (int i = 0; i < 4; ++i) {
                mlsh[qsub][0][lg * 4 + i] = mrun[i];
                mlsh[qsub][1][lg * 4 + i] = lrun[i];
            }
        }
#pragma unroll
        for (int ot = 0; ot < 4; ++ot)
#pragma unroll
            for (int i = 0; i < 4; ++i) Osh[qsub][lg * 4 + i][ot * 16 + lr] = oacc[ot][i];
    }
    __syncthreads();
    if (ks == 0) {
#pragma unroll
        for (int ot = 0; ot < 4; ++ot)
#pragma unroll
            for (int i = 0; i < 4; ++i) {
                const int row = lg * 4 + i;
                const float m1 = mlsh[qsub][0][row], l1 = mlsh[qsub][1][row];
                const float mm = fmaxf(mrun[i], m1);
                const float fa = __expf(mrun[i] - mm), fb = __expf(m1 - mm);
                const float ll = lrun[i] * fa + l1 * fb;
                const float v = (oacc[ot][i] * fa + Osh[qsub][row][ot * 16 + lr] * fb) / ll;
                out[(size_t)(qr0 + row) * 768 + h * 64 + ot * 16 + lr] = (bf16_t)v;
            }
    }
}

// ---------------- launch ----------------
extern "C" void kernel_launch(void* const* d_in, const int* in_sizes, int n_in, void* d_out,
                              int out_size, void* d_ws, size_t ws_size, hipStream_t stream) {
    const int* ids = (const int*)d_in[0];
    const float* wte = (const float*)d_in[1];
    const float* wpe = (const float*)d_in[2];
    const float* ln1_w = (const float*)d_in[3];
    const float* ln1_b = (const float*)d_in[4];
    const float* qkv_w = (const float*)d_in[5];
    const float* qkv_b = (const float*)d_in[6];
    const float* out_w = (const float*)d_in[7];
    const float* out_b = (const float*)d_in[8];
    const float* ln2_w = (const float*)d_in[9];
    const float* ln2_b = (const float*)d_in[10];
    const float* up_w = (const float*)d_in[11];
    const float* up_b = (const float*)d_in[12];
    const float* down_w = (const float*)d_in[13];
    const float* down_b = (const float*)d_in[14];
    const float* lnf_w = (const float*)d_in[15];
    const float* lnf_b = (const float*)d_in[16];

    char* ws = (char*)d_ws;
    float* x = (float*)(ws + 0);                 // 3 MB
    bf16_t* a_bf = (bf16_t*)(ws + 3145728);      // 1.5 MB
    bf16_t* qkv_bf = (bf16_t*)(ws + 4718592);    // 4.5 MB
    bf16_t* attn_bf = (bf16_t*)(ws + 9437184);   // 1.5 MB
    bf16_t* u_bf = (bf16_t*)(ws + 11010048);     // 6 MB (first half doubles as vt)
    bf16_t* vt = (bf16_t*)(ws + 11010048);       // 1.5 MB; dead before u_bf written
    // split-K partials overlay qkv_bf+attn_bf region (lifetimes disjoint in sequence)
    float* p0 = (float*)(ws + 4718592);          // 3 MB
    float* p1 = (float*)(ws + 7864320);          // 3 MB
    bf16_t* wqkv_t = (bf16_t*)(ws + 17301504);   // [12][2304][768]
    bf16_t* wout_t = (bf16_t*)(ws + 59768832);   // [12][768][768]
    bf16_t* wup_t = (bf16_t*)(ws + 73924608);    // [12][3072][768]
    bf16_t* wdown_t = (bf16_t*)(ws + 130547712); // [12][768][3072]

    float* outF = (float*)d_out;
    const size_t SD = (size_t)1024 * 768;
    float* out_layers = outF + SD;  // [13][1024][768]

    transpose_cvt<<<dim3(72, 24, 12), 256, 0, stream>>>(qkv_w, wqkv_t, 768, 2304);
    transpose_cvt<<<dim3(24, 24, 12), 256, 0, stream>>>(out_w, wout_t, 768, 768);
    transpose_cvt<<<dim3(96, 24, 12), 256, 0, stream>>>(up_w, wup_t, 768, 3072);
    transpose_cvt<<<dim3(24, 96, 12), 256, 0, stream>>>(down_w, wdown_t, 3072, 768);

    embed_kernel<<<1024, 256, 0, stream>>>(ids, wte, wpe, x, out_layers);

    for (int l = 0; l < 12; ++l) {
        const size_t l768 = (size_t)l * 768;
        if (l == 0)
            ln_kernel<true><<<1024, 256, 0, stream>>>(x, ln1_w, ln1_b, a_bf);
        else
            ln_reduce<false><<<1024, 256, 0, stream>>>(p0, p1, down_b + (l - 1) * 768, x,
                                                       out_layers + (size_t)l * SD, a_bf,
                                                       ln1_w + l768, ln1_b + l768);
        gemm3<64, 64, false, false, true><<<dim3(16, 36), 256, 0, stream>>>(
            a_bf, wqkv_t + (size_t)l * 2304 * 768, qkv_b + (size_t)l * 2304, nullptr, nullptr,
            qkv_bf, vt, 2304, 768, 768);
        attn4_kernel<<<dim3(32, 12), 256, 0, stream>>>(qkv_bf, vt, attn_bf);
        gemm3<64, 64, false, true, false><<<dim3(16, 12), 256, 0, stream>>>(
            attn_bf, wout_t + (size_t)l * 768 * 768, out_b + l768, x, x, nullptr, nullptr, 768,
            768, 768);
        ln_kernel<true><<<1024, 256, 0, stream>>>(x, ln2_w + l768, ln2_b + l768, a_bf);
        gemm3<64, 64, true, false, false><<<dim3(16, 48), 256, 0, stream>>>(
            a_bf, wup_t + (size_t)l * 3072 * 768, up_b + (size_t)l * 3072, nullptr, nullptr,
            u_bf, nullptr, 3072, 768, 768);
        gemm3<64, 64, false, false, false><<<dim3(16, 12, 2), 256, 0, stream>>>(
            u_bf, wdown_t + (size_t)l * 768 * 3072, nullptr, nullptr, p0, nullptr, nullptr, 768,
            3072, 1536);
    }
    ln_reduce<true><<<1024, 256, 0, stream>>>(p0, p1, down_b + 11 * 768, x,
                                              out_layers + 12 * SD, outF, lnf_w, lnf_b);
}

// Round 15
// 1077.391 us; speedup vs baseline: 1.4948x; 1.0050x over previous
//
#include <hip/hip_runtime.h>

typedef __bf16 bf16_t;
typedef __bf16 bf16x8 __attribute__((ext_vector_type(8)));
typedef __bf16 bf16x4 __attribute__((ext_vector_type(4)));
typedef float f32x4 __attribute__((ext_vector_type(4)));

#define MFMA16(a, b, c) __builtin_amdgcn_mfma_f32_16x16x32_bf16(a, b, c, 0, 0, 0)

__device__ __forceinline__ f32x4 zero4() {
    f32x4 z = {0.f, 0.f, 0.f, 0.f};
    return z;
}

__device__ __forceinline__ float gelu_f(float v) {
    float u = 0.7978845608028654f * (v + 0.044715f * v * v * v);
    float e = __expf(2.0f * u);
    float th = 1.0f - 2.0f / (e + 1.0f);  // tanh(u), overflow-safe
    return 0.5f * v * (1.0f + th);
}

__device__ __forceinline__ void gload16(const bf16_t* g, bf16_t* l) {
    __builtin_amdgcn_global_load_lds((const __attribute__((address_space(1))) void*)g,
                                     (__attribute__((address_space(3))) void*)l, 16, 0, 0);
}

// ---------------- embedding: x = wte[ids] + wpe; also layers_output[0] ----------------
__global__ __launch_bounds__(256) void embed_kernel(const int* __restrict__ ids,
                                                    const float* __restrict__ wte,
                                                    const float* __restrict__ wpe,
                                                    float* __restrict__ x,
                                                    float* __restrict__ out0) {
    const int s = blockIdx.x;
    const int id = ids[s];
    const size_t base = (size_t)s * 768;
#pragma unroll
    for (int r = 0; r < 3; ++r) {
        int d = threadIdx.x + r * 256;
        float v = wte[(size_t)id * 768 + d] + wpe[base + d];
        x[base + d] = v;
        out0[base + d] = v;
    }
}

// ---------------- layernorm: one row per block ----------------
template <bool BF16OUT>
__global__ __launch_bounds__(256) void ln_kernel(const float* __restrict__ x,
                                                 const float* __restrict__ w,
                                                 const float* __restrict__ b,
                                                 void* __restrict__ outp) {
    const int row = blockIdx.x;
    const int t = threadIdx.x;
    const float* xr = x + (size_t)row * 768;
    float v0 = xr[t], v1 = xr[t + 256], v2 = xr[t + 512];
    float s = v0 + v1 + v2;
    float q = v0 * v0 + v1 * v1 + v2 * v2;
#pragma unroll
    for (int off = 32; off >= 1; off >>= 1) {
        s += __shfl_xor(s, off);
        q += __shfl_xor(q, off);
    }
    __shared__ float sh_s[4], sh_q[4];
    if ((t & 63) == 0) {
        sh_s[t >> 6] = s;
        sh_q[t >> 6] = q;
    }
    __syncthreads();
    s = sh_s[0] + sh_s[1] + sh_s[2] + sh_s[3];
    q = sh_q[0] + sh_q[1] + sh_q[2] + sh_q[3];
    const float mean = s * (1.0f / 768.0f);
    const float var = q * (1.0f / 768.0f) - mean * mean;
    const float rstd = rsqrtf(var + 1e-5f);
    float vv[3] = {v0, v1, v2};
#pragma unroll
    for (int r = 0; r < 3; ++r) {
        int d = t + r * 256;
        float y = (vv[r] - mean) * rstd * w[d] + b[d];
        if (BF16OUT)
            ((bf16_t*)outp)[(size_t)row * 768 + d] = (bf16_t)y;
        else
            ((float*)outp)[(size_t)row * 768 + d] = y;
    }
}

// ------- fused: x += p0 + p1 + down_bias; write out_layers slice; LN -> lnout ---------
template <bool FINAL>
__global__ __launch_bounds__(256) void ln_reduce(const float* __restrict__ p0,
                                                 const float* __restrict__ p1,
                                                 const float* __restrict__ db,
                                                 float* __restrict__ x,
                                                 float* __restrict__ slice,
                                                 void* __restrict__ lnout,
                                                 const float* __restrict__ w,
                                                 const float* __restrict__ b) {
    const int row = blockIdx.x;
    const int t = threadIdx.x;
    const size_t base = (size_t)row * 768;
    float vv[3];
#pragma unroll
    for (int r = 0; r < 3; ++r) {
        int d = t + r * 256;
        float v = x[base + d] + p0[base + d] + p1[base + d] + db[d];
        vv[r] = v;
        x[base + d] = v;
        slice[base + d] = v;
    }
    float s = vv[0] + vv[1] + vv[2];
    float q = vv[0] * vv[0] + vv[1] * vv[1] + vv[2] * vv[2];
#pragma unroll
    for (int off = 32; off >= 1; off >>= 1) {
        s += __shfl_xor(s, off);
        q += __shfl_xor(q, off);
    }
    __shared__ float sh_s[4], sh_q[4];
    if ((t & 63) == 0) {
        sh_s[t >> 6] = s;
        sh_q[t >> 6] = q;
    }
    __syncthreads();
    s = sh_s[0] + sh_s[1] + sh_s[2] + sh_s[3];
    q = sh_q[0] + sh_q[1] + sh_q[2] + sh_q[3];
    const float mean = s * (1.0f / 768.0f);
    const float var = q * (1.0f / 768.0f) - mean * mean;
    const float rstd = rsqrtf(var + 1e-5f);
#pragma unroll
    for (int r = 0; r < 3; ++r) {
        int d = t + r * 256;
        float y = (vv[r] - mean) * rstd * w[d] + b[d];
        if (FINAL)
            ((float*)lnout)[base + d] = y;
        else
            ((bf16_t*)lnout)[base + d] = (bf16_t)y;
    }
}

// ------- weight transpose + f32->bf16: src[z][K][N] -> dst[z][N][K], all layers -------
__global__ __launch_bounds__(256) void transpose_cvt(const float* __restrict__ src0,
                                                     bf16_t* __restrict__ dst0, int K, int N) {
    const int l = blockIdx.z;
    const float* src = src0 + (size_t)l * K * N;
    bf16_t* dst = dst0 + (size_t)l * N * K;
    const int n0 = blockIdx.x * 32;
    const int k0 = blockIdx.y * 32;
    __shared__ float tile[32][36];
    const int t = threadIdx.x;
    const int r = t >> 3, c4 = (t & 7) * 4;
    const float4 v = *(const float4*)&src[(size_t)(k0 + r) * N + n0 + c4];
    tile[r][c4 + 0] = v.x;
    tile[r][c4 + 1] = v.y;
    tile[r][c4 + 2] = v.z;
    tile[r][c4 + 3] = v.w;
    __syncthreads();
    bf16x4 o;
    o[0] = (bf16_t)tile[c4 + 0][r];
    o[1] = (bf16_t)tile[c4 + 1][r];
    o[2] = (bf16_t)tile[c4 + 2][r];
    o[3] = (bf16_t)tile[c4 + 3][r];
    *(bf16x4*)&dst[(size_t)(n0 + r) * K + k0 + c4] = o;
}

// --------- GEMM: C[1024,N] = A[1024,LDK] x BT[N,LDK]^T over KLEN (z split) ------------
// 4 waves (2x2), BK=64, global_load_lds staging, XOR-swizzled row-major LDS.
// T3/T4: 3-buffer rotation, prefetch depth 2, raw s_barrier + COUNTED s_waitcnt vmcnt(N).
// T5: setprio(1) around the MFMA compute phase.
// VT: also scatter transposed V (cols>=1536 of qkv) to vt[768][1024].
template <int BM, int BN, bool GELU, bool RES, bool VT>
__global__ __launch_bounds__(256) void gemm3(const bf16_t* __restrict__ A,
                                             const bf16_t* __restrict__ BT,
                                             const float* __restrict__ bias,
                                             const float* __restrict__ res,
                                             float* __restrict__ outF,
                                             bf16_t* __restrict__ outB,
                                             bf16_t* __restrict__ vt, int N, int LDK,
                                             int KLEN) {
    constexpr int MW = BM / 32, NW = BN / 32;
    constexpr int TILE = (BM + BN) * 64;
    constexpr int LOADS = (BM + BN) / 32;  // gload16s per thread per stage
    __shared__ __align__(16) bf16_t lds[3 * TILE];
    const int tid = threadIdx.x;
    const int lane = tid & 63, wv = tid >> 6, wm = wv >> 1, wn = wv & 1;
    const int lr = lane & 15, lg = lane >> 4;
    const int m0 = blockIdx.x * BM, n0 = blockIdx.y * BN;
    const bf16_t* Ap = A + (size_t)m0 * LDK + (size_t)blockIdx.z * KLEN;
    const bf16_t* Bp = BT + (size_t)n0 * LDK + (size_t)blockIdx.z * KLEN;

    f32x4 acc[MW][NW];
#pragma unroll
    for (int i = 0; i < MW; ++i)
#pragma unroll
        for (int j = 0; j < NW; ++j) acc[i][j] = zero4();

    const int KT = KLEN >> 6;

    auto stage = [&](int buf, int kt) {
        bf16_t* Ad = lds + buf * TILE;
        bf16_t* Bd = Ad + BM * 64;
#pragma unroll
        for (int i = 0; i < BM / 32; ++i) {
            int v = i * 256 + tid;
            int row = v >> 3, cg = v & 7;
            gload16(Ap + (size_t)row * LDK + kt * 64 + ((cg ^ (row & 7)) << 3), Ad + v * 8);
        }
#pragma unroll
        for (int i = 0; i < BN / 32; ++i) {
            int v = i * 256 + tid;
            int row = v >> 3, cg = v & 7;
            gload16(Bp + (size_t)row * LDK + kt * 64 + ((cg ^ (row & 7)) << 3), Bd + v * 8);
        }
    };

    stage(0, 0);
    stage(1, 1);  // KT >= 6 always here
    int buf = 0;
    for (int kt = 0; kt < KT; ++kt) {
        // wait for tile kt's loads only; keep tile kt+1's in flight across the barrier
        if (kt + 1 < KT) {
            if constexpr (LOADS == 4)
                asm volatile("s_waitcnt vmcnt(4)" ::: "memory");
            else
                asm volatile("s_waitcnt vmcnt(3)" ::: "memory");
        } else {
            asm volatile("s_waitcnt vmcnt(0)" ::: "memory");
        }
        __builtin_amdgcn_s_barrier();
        if (kt + 2 < KT) stage((kt + 2) % 3, kt + 2);
        const bf16_t* Ab = lds + buf * TILE;
        const bf16_t* Bb = Ab + BM * 64;
        __builtin_amdgcn_s_setprio(1);  // T5
#pragma unroll
        for (int c = 0; c < 2; ++c) {
            bf16x8 af[MW], bfr[NW];
#pragma unroll
            for (int i = 0; i < MW; ++i) {
                int row = wm * (BM / 2) + i * 16 + lr;
                af[i] = *(const bf16x8*)&Ab[row * 64 + ((c * 32 + lg * 8) ^ ((row & 7) << 3))];
            }
#pragma unroll
            for (int j = 0; j < NW; ++j) {
                int row = wn * (BN / 2) + j * 16 + lr;
                bfr[j] = *(const bf16x8*)&Bb[row * 64 + ((c * 32 + lg * 8) ^ ((row & 7) << 3))];
            }
#pragma unroll
            for (int i = 0; i < MW; ++i)
#pragma unroll
                for (int j = 0; j < NW; ++j) acc[i][j] = MFMA16(af[i], bfr[j], acc[i][j]);
        }
        __builtin_amdgcn_s_setprio(0);
        buf = (buf + 1) % 3;
    }

    float* o1 = outF ? outF + (size_t)blockIdx.z * ((size_t)1024 * N) : nullptr;
    // epilogue: C/D layout col = lane&15, row = (lane>>4)*4 + reg
#pragma unroll
    for (int i = 0; i < MW; ++i) {
#pragma unroll
        for (int j = 0; j < NW; ++j) {
            const int col = n0 + wn * (BN / 2) + j * 16 + lr;
            const float bc = bias ? bias[col] : 0.f;
            float vr[4];
#pragma unroll
            for (int ii = 0; ii < 4; ++ii) {
                const int rrow = m0 + wm * (BM / 2) + i * 16 + lg * 4 + ii;
                float v = acc[i][j][ii] + bc;
                if (GELU) v = gelu_f(v);
                if (RES) v += res[(size_t)rrow * N + col];
                if (o1) o1[(size_t)rrow * N + col] = v;
                if (outB) outB[(size_t)rrow * N + col] = (bf16_t)v;
                vr[ii] = v;
            }
            if (VT && col >= 1536) {  // transposed V: vt[d'][seq], 4 consecutive rows
                const int rrow0 = m0 + wm * (BM / 2) + i * 16 + lg * 4;
                bf16x4 o;
#pragma unroll
                for (int ii = 0; ii < 4; ++ii) o[ii] = (bf16_t)vr[ii];
                *(bf16x4*)&vt[(size_t)(col - 1536) * 1024 + rrow0] = o;
            }
        }
    }
}

// ------- flash attention v4: balanced 2x2 wave split, gload_lds+swizzle staging -------
__global__ __launch_bounds__(256) void attn4_kernel(const bf16_t* __restrict__ qkv,
                                                    const bf16_t* __restrict__ vt,
                                                    bf16_t* __restrict__ out) {
    const int qb = 31 - blockIdx.x;  // big blocks first
    const int h = blockIdx.y;
    const int tid = threadIdx.x;
    const int w = tid >> 6, lane = tid & 63;
    const int lr = lane & 15, lg = lane >> 4;
    const int qsub = w & 1, ks = w >> 1;
    const int q0 = qb * 32;
    const int qr0 = q0 + qsub * 16;
    const int NT = (q0 >> 6) + 1;

    __shared__ __align__(16) bf16_t Ksh[2][64 * 64];
    __shared__ __align__(16) bf16_t Vsh[2][64 * 64];
    __shared__ bf16_t Ps[4][16][72];
    __shared__ float Osh[2][16][64];
    __shared__ float mlsh[2][2][16];

    bf16x8 aq[2];
    {
        const size_t qoff = (size_t)(qr0 + lr) * 2304 + h * 64;
#pragma unroll
        for (int dt = 0; dt < 2; ++dt) {
            bf16x8 v = *(const bf16x8*)&qkv[qoff + dt * 32 + lg * 8];
#pragma unroll
            for (int i = 0; i < 8; ++i) v[i] = (bf16_t)((float)v[i] * 0.125f);
            aq[dt] = v;
        }
    }

    f32x4 oacc[4];
#pragma unroll
    for (int i = 0; i < 4; ++i) oacc[i] = zero4();
    float mrun[4], lrun[4];
#pragma unroll
    for (int i = 0; i < 4; ++i) {
        mrun[i] = -3.0e38f;
        lrun[i] = 0.f;
    }

    const int st = tid >> 7, tt = tid & 127;
    const int rounds = (NT + 1) >> 1;

    for (int rr = 0; rr < rounds; ++rr) {
        const int skb = 2 * rr + st;
        if (skb < NT) {
            const int k0s = skb * 64;
#pragma unroll
            for (int i = 0; i < 4; ++i) {
                int v = i * 128 + tt;
                int row = v >> 3, cg = v & 7;
                gload16(qkv + (size_t)(k0s + row) * 2304 + 768 + h * 64 +
                            ((cg ^ (row & 7)) << 3),
                        &Ksh[st][v * 8]);
            }
#pragma unroll
            for (int i = 0; i < 4; ++i) {
                int v = i * 128 + tt;
                int row = v >> 3, cg = v & 7;
                gload16(vt + (size_t)(h * 64 + row) * 1024 + k0s + ((cg ^ (row & 7)) << 3),
                        &Vsh[st][v * 8]);
            }
        }
        __syncthreads();

        const int kb = 2 * rr + ks;
        if (kb < NT) {
            const int k0 = kb * 64;
            f32x4 sacc[4];
#pragma unroll
            for (int i = 0; i < 4; ++i) sacc[i] = zero4();
            __builtin_amdgcn_s_setprio(1);
#pragma unroll
            for (int kt = 0; kt < 4; ++kt) {
                const int row = kt * 16 + lr;
#pragma unroll
                for (int dt = 0; dt < 2; ++dt) {
                    bf16x8 bk = *(const bf16x8*)&Ksh[ks][row * 64 +
                                                        ((dt * 32 + lg * 8) ^ ((row & 7) << 3))];
                    sacc[kt] = MFMA16(aq[dt], bk, sacc[kt]);
                }
            }
            __builtin_amdgcn_s_setprio(0);

            if (kb == NT - 1) {
#pragma unroll
                for (int kt = 0; kt < 4; ++kt)
#pragma unroll
                    for (int i = 0; i < 4; ++i)
                        if (k0 + kt * 16 + lr > qr0 + lg * 4 + i) sacc[kt][i] = -3.0e38f;
            }

#pragma unroll
            for (int i = 0; i < 4; ++i) {
                float rmax = fmaxf(fmaxf(sacc[0][i], sacc[1][i]), fmaxf(sacc[2][i], sacc[3][i]));
                rmax = fmaxf(rmax, __shfl_xor(rmax, 1));
                rmax = fmaxf(rmax, __shfl_xor(rmax, 2));
                rmax = fmaxf(rmax, __shfl_xor(rmax, 4));
                rmax = fmaxf(rmax, __shfl_xor(rmax, 8));
                const float mnew = fmaxf(mrun[i], rmax);
                const float sf = __expf(mrun[i] - mnew);
                mrun[i] = mnew;
                float rsum = 0.f;
#pragma unroll
                for (int kt = 0; kt < 4; ++kt) {
                    float p = __expf(sacc[kt][i] - mnew);
                    rsum += p;
                    Ps[w][lg * 4 + i][kt * 16 + lr] = (bf16_t)p;
                }
                rsum += __shfl_xor(rsum, 1);
                rsum += __shfl_xor(rsum, 2);
                rsum += __shfl_xor(rsum, 4);
                rsum += __shfl_xor(rsum, 8);
                lrun[i] = lrun[i] * sf + rsum;
#pragma unroll
                for (int ot = 0; ot < 4; ++ot) oacc[ot][i] *= sf;
            }

            bf16x8 pa0 = *(const bf16x8*)&Ps[w][lr][lg * 8];
            bf16x8 pa1 = *(const bf16x8*)&Ps[w][lr][32 + lg * 8];
            __builtin_amdgcn_s_setprio(1);
#pragma unroll
            for (int ot = 0; ot < 4; ++ot) {
                const int row = ot * 16 + lr;
                bf16x8 bv0 = *(const bf16x8*)&Vsh[ks][row * 64 + ((lg * 8) ^ ((row & 7) << 3))];
                bf16x8 bv1 =
                    *(const bf16x8*)&Vsh[ks][row * 64 + ((32 + lg * 8) ^ ((row & 7) << 3))];
                oacc[ot] = MFMA16(pa0, bv0, oacc[ot]);
                oacc[ot] = MFMA16(pa1, bv1, oacc[ot]);
            }
            __builtin_amdgcn_s_setprio(0);
        }
        __syncthreads();
    }

    if (ks == 1) {
        if (lr == 0) {
#pragma unroll
            for (int i = 0; i < 4; ++i) {
                mlsh[qsub][0][lg * 4 + i] = mrun[i];
                mlsh[qsub][1][lg * 4 + i] = lrun[i];
            }
        }
#pragma unroll
        for (int ot = 0; ot < 4; ++ot)
#pragma unroll
            for (int i = 0; i < 4; ++i) Osh[qsub][lg * 4 + i][ot * 16 + lr] = oacc[ot][i];
    }
    __syncthreads();
    if (ks == 0) {
#pragma unroll
        for (int ot = 0; ot < 4; ++ot)
#pragma unroll
            for (int i = 0; i < 4; ++i) {
                const int row = lg * 4 + i;
                const float m1 = mlsh[qsub][0][row], l1 = mlsh[qsub][1][row];
                const float mm = fmaxf(mrun[i], m1);
                const float fa = __expf(mrun[i] - mm), fb = __expf(m1 - mm);
                const float ll = lrun[i] * fa + l1 * fb;
                const float v = (oacc[ot][i] * fa + Osh[qsub][row][ot * 16 + lr] * fb) / ll;
                out[(size_t)(qr0 + row) * 768 + h * 64 + ot * 16 + lr] = (bf16_t)v;
            }
    }
}

// ---------------- launch ----------------
extern "C" void kernel_launch(void* const* d_in, const int* in_sizes, int n_in, void* d_out,
                              int out_size, void* d_ws, size_t ws_size, hipStream_t stream) {
    const int* ids = (const int*)d_in[0];
    const float* wte = (const float*)d_in[1];
    const float* wpe = (const float*)d_in[2];
    const float* ln1_w = (const float*)d_in[3];
    const float* ln1_b = (const float*)d_in[4];
    const float* qkv_w = (const float*)d_in[5];
    const float* qkv_b = (const float*)d_in[6];
    const float* out_w = (const float*)d_in[7];
    const float* out_b = (const float*)d_in[8];
    const float* ln2_w = (const float*)d_in[9];
    const float* ln2_b = (const float*)d_in[10];
    const float* up_w = (const float*)d_in[11];
    const float* up_b = (const float*)d_in[12];
    const float* down_w = (const float*)d_in[13];
    const float* down_b = (const float*)d_in[14];
    const float* lnf_w = (const float*)d_in[15];
    const float* lnf_b = (const float*)d_in[16];

    char* ws = (char*)d_ws;
    float* x = (float*)(ws + 0);                 // 3 MB
    bf16_t* a_bf = (bf16_t*)(ws + 3145728);      // 1.5 MB
    bf16_t* qkv_bf = (bf16_t*)(ws + 4718592);    // 4.5 MB
    bf16_t* attn_bf = (bf16_t*)(ws + 9437184);   // 1.5 MB
    bf16_t* u_bf = (bf16_t*)(ws + 11010048);     // 6 MB (first half doubles as vt)
    bf16_t* vt = (bf16_t*)(ws + 11010048);       // 1.5 MB; dead before u_bf written
    // split-K partials overlay qkv_bf+attn_bf region (lifetimes disjoint in sequence)
    float* p0 = (float*)(ws + 4718592);          // 3 MB
    float* p1 = (float*)(ws + 7864320);          // 3 MB
    bf16_t* wqkv_t = (bf16_t*)(ws + 17301504);   // [12][2304][768]
    bf16_t* wout_t = (bf16_t*)(ws + 59768832);   // [12][768][768]
    bf16_t* wup_t = (bf16_t*)(ws + 73924608);    // [12][3072][768]
    bf16_t* wdown_t = (bf16_t*)(ws + 130547712); // [12][768][3072]

    float* outF = (float*)d_out;
    const size_t SD = (size_t)1024 * 768;
    float* out_layers = outF + SD;  // [13][1024][768]

    transpose_cvt<<<dim3(72, 24, 12), 256, 0, stream>>>(qkv_w, wqkv_t, 768, 2304);
    transpose_cvt<<<dim3(24, 24, 12), 256, 0, stream>>>(out_w, wout_t, 768, 768);
    transpose_cvt<<<dim3(96, 24, 12), 256, 0, stream>>>(up_w, wup_t, 768, 3072);
    transpose_cvt<<<dim3(24, 96, 12), 256, 0, stream>>>(down_w, wdown_t, 3072, 768);

    embed_kernel<<<1024, 256, 0, stream>>>(ids, wte, wpe, x, out_layers);

    for (int l = 0; l < 12; ++l) {
        const size_t l768 = (size_t)l * 768;
        if (l == 0)
            ln_kernel<true><<<1024, 256, 0, stream>>>(x, ln1_w, ln1_b, a_bf);
        else
            ln_reduce<false><<<1024, 256, 0, stream>>>(p0, p1, down_b + (l - 1) * 768, x,
                                                       out_layers + (size_t)l * SD, a_bf,
                                                       ln1_w + l768, ln1_b + l768);
        gemm3<64, 64, false, false, true><<<dim3(16, 36), 256, 0, stream>>>(
            a_bf, wqkv_t + (size_t)l * 2304 * 768, qkv_b + (size_t)l * 2304, nullptr, nullptr,
            qkv_bf, vt, 2304, 768, 768);
        attn4_kernel<<<dim3(32, 12), 256, 0, stream>>>(qkv_bf, vt, attn_bf);
        gemm3<32, 64, false, true, false><<<dim3(32, 12), 256, 0, stream>>>(
            attn_bf, wout_t + (size_t)l * 768 * 768, out_b + l768, x, x, nullptr, nullptr, 768,
            768, 768);
        ln_kernel<true><<<1024, 256, 0, stream>>>(x, ln2_w + l768, ln2_b + l768, a_bf);
        gemm3<64, 64, true, false, false><<<dim3(16, 48), 256, 0, stream>>>(
            a_bf, wup_t + (size_t)l * 3072 * 768, up_b + (size_t)l * 3072, nullptr, nullptr,
            u_bf, nullptr, 3072, 768, 768);
        gemm3<32, 64, false, false, false><<<dim3(32, 12, 2), 256, 0, stream>>>(
            u_bf, wdown_t + (size_t)l * 768 * 3072, nullptr, nullptr, p0, nullptr, nullptr, 768,
            3072, 1536);
    }
    ln_reduce<true><<<1024, 256, 0, stream>>>(p0, p1, down_b + 11 * 768, x,
                                              out_layers + 12 * SD, outF, lnf_w, lnf_b);
}